// Round 8
// baseline (235.195 us; speedup 1.0000x reference)
//
#include <hip/hip_runtime.h>
#include <stdint.h>

#define TEMP 0.25f   // 1/sqrt(d), d=16

typedef unsigned short u16;
typedef short v8s __attribute__((ext_vector_type(8)));
typedef float v4f __attribute__((ext_vector_type(4)));

static __device__ __forceinline__ uint32_t f2b_bits(float f){
    union { float f; uint32_t i; } x; x.f = f;
    uint32_t u = x.i;
    return (u + 0x7FFFu + ((u >> 16) & 1u)) >> 16;   // RNE to bf16 (as u16)
}
static __device__ __forceinline__ float b2f(u16 u){
    union { uint32_t i; float f; } x; x.i = ((uint32_t)u) << 16; return x.f;
}
static __device__ __forceinline__ float bl(uint32_t u){
    union { uint32_t i; float f; } x; x.i = u << 16; return x.f;
}
static __device__ __forceinline__ float bh(uint32_t u){
    union { uint32_t i; float f; } x; x.i = u & 0xffff0000u; return x.f;
}
static __device__ __forceinline__ uint4 pack8(const uint32_t* e){
    return make_uint4(e[0] | (e[1] << 16), e[2] | (e[3] << 16),
                      e[4] | (e[5] << 16), e[6] | (e[7] << 16));
}
union U8S { uint4 u; v8s s; };
union I4S { int i[4]; v8s s; };
static __device__ __forceinline__ v8s asv8s(uint4 u){ U8S x; x.u = u; return x.s; }
static __device__ __forceinline__ v8s swapq(v8s v){   // lane^32: [X|Y] -> [Y|X]
    union { v8s s; int i[4]; } x; x.s = v;
    #pragma unroll
    for (int k = 0; k < 4; ++k) x.i[k] = __shfl_xor(x.i[k], 32);
    return x.s;
}

// ---------------------------------------------------------------------------
// pack_coarse: K_coarse -> frag-order bf16 split arrays KP1=[K0|K1], KP3=[K2|K0];
// V_coarse -> VP1=[V0|V1]. Grid (32 bh, 2 kv, 8 kt-slice) = 512 blocks so the
// launch is latency-hidden (round 7's 64-block version was a ~35us bubble).
// ---------------------------------------------------------------------------
__global__ __launch_bounds__(256)
void pack_coarse(const float* __restrict__ kc, const float* __restrict__ vc,
                 uint4* __restrict__ KP1, uint4* __restrict__ KP3,
                 uint4* __restrict__ VP1)
{
    const int bh = blockIdx.x;        // 0..31
    const int kv = blockIdx.y;        // 0:K 1:V
    const int z  = blockIdx.z;        // 0..7 (8 kt each)
    const int b = bh >> 3, h = bh & 7;
    const int tid = threadIdx.x;
    const size_t sbase = (size_t)(b * 128 + h * 16) * 1024;
    const size_t fbase = (size_t)bh * 64 * 64;

    #pragma unroll
    for (int it = 0; it < 2; ++it){
        int task = it * 256 + tid;    // 512 frag entries in this slice
        int kt = z * 8 + (task >> 6), ln = task & 63;
        int quad = ln >> 4, col = ln & 15;
        if (kv == 0){
            uint32_t e1[8], e3[8];
            #pragma unroll
            for (int j = 0; j < 8; ++j){
                int dch = (quad & 1) * 8 + j;
                float x = kc[sbase + (size_t)dch * 1024 + kt * 16 + col];
                uint32_t u0 = f2b_bits(x);
                float r1 = x - b2f((u16)u0);
                uint32_t u1 = f2b_bits(r1);
                float r2 = r1 - b2f((u16)u1);
                uint32_t u2 = f2b_bits(r2);
                e1[j] = (quad < 2) ? u0 : u1;
                e3[j] = (quad < 2) ? u2 : u0;
            }
            KP1[fbase + kt * 64 + ln] = pack8(e1);
            KP3[fbase + kt * 64 + ln] = pack8(e3);
        } else {
            uint32_t e[8];
            #pragma unroll
            for (int j = 0; j < 8; ++j){
                int key = kt * 16 + (quad & 1) * 8 + j;
                float x = vc[sbase + (size_t)col * 1024 + key];
                uint32_t u0 = f2b_bits(x);
                uint32_t u1 = f2b_bits(x - b2f((u16)u0));
                e[j] = (quad < 2) ? u0 : u1;
            }
            VP1[fbase + kt * 64 + ln] = pack8(e);
        }
    }
}

// ---------------------------------------------------------------------------
// coarse_mfma v2: block 512 (8 waves) per (b,h,16-row tile). Each wave owns a
// 128-key strip (8 MFMA k-tiles). Scores in C-layout regs (sc[8] = 32 VGPR ->
// higher occupancy than round 7's 64). PV: u32-packed (P0|P1) LDS transpose,
// b128 reads + v_perm extraction. Top-k: exact fp32 compares (proven), 8-way
// cross-wave merge.
// ---------------------------------------------------------------------------
__global__ __launch_bounds__(512, 4)
void coarse_mfma(const float* __restrict__ qc,
                 const uint4* __restrict__ KP1, const uint4* __restrict__ KP3,
                 const uint4* __restrict__ VP1,
                 float* __restrict__ msg0, int* __restrict__ topk_out)
{
    const int ltile = blockIdx.x;   // 0..63
    const int h = blockIdx.y, b = blockIdx.z;
    const int bh = b * 8 + h;
    const int tid = threadIdx.x, lane = tid & 63, wv = tid >> 6;  // wv 0..7
    const int quad = lane >> 4, col = lane & 15;
    const int lbase = ltile * 16;

    __shared__ uint32_t tls[8][16 * 20];   // packed P0|P1, stride 20 u32 (16B-aligned rows)
    __shared__ float rred[2][8][16];       // [max|sum][wave][row]
    __shared__ float pvred[8][16][16];
    __shared__ float tkv[8][16][8];
    __shared__ int   tki[8][16][8];

    // ---- A-frags from Q (3-term bf16 split; TEMP folded in, exact pow2)
    v8s a1, a3;
    {
        int row = lbase + col;
        int dch0 = (quad & 1) * 8;
        #pragma unroll
        for (int j = 0; j < 8; ++j){
            float x = qc[(size_t)(b * 128 + h * 16 + dch0 + j) * 1024 + row] * TEMP;
            uint32_t u0 = f2b_bits(x);
            float r1 = x - b2f((u16)u0);
            uint32_t u1 = f2b_bits(r1);
            float r2 = r1 - b2f((u16)u1);
            uint32_t u2 = f2b_bits(r2);
            a1[j] = (short)(quad < 2 ? u0 : u1);
            a3[j] = (short)(quad < 2 ? u0 : u2);
        }
    }

    // ---- scores: 8 C-tiles (rows lbase.., cols = keys wv*128 + kt*16 + col)
    const size_t fbase = (size_t)bh * 64 * 64;
    v4f sc[8];
    #pragma unroll
    for (int kt = 0; kt < 8; ++kt){
        int ktg = wv * 8 + kt;
        v8s b1 = asv8s(KP1[fbase + (size_t)ktg * 64 + lane]);
        v8s b3 = asv8s(KP3[fbase + (size_t)ktg * 64 + lane]);
        v8s b2 = swapq(b1);                         // [K1|K0]
        v4f c = {0.f, 0.f, 0.f, 0.f};
        c = __builtin_amdgcn_mfma_f32_16x16x32_bf16(a1, b1, c, 0, 0, 0); // Q0K0+Q1K1
        c = __builtin_amdgcn_mfma_f32_16x16x32_bf16(a1, b2, c, 0, 0, 0); // Q0K1+Q1K0
        c = __builtin_amdgcn_mfma_f32_16x16x32_bf16(a3, b3, c, 0, 0, 0); // Q0K2+Q2K0
        sc[kt] = c;
    }

    // ---- softmax: per-wave row max -> cross-wave -> exp -> row sums
    #pragma unroll
    for (int r = 0; r < 4; ++r){
        float m = sc[0][r];
        #pragma unroll
        for (int kt = 1; kt < 8; ++kt) m = fmaxf(m, sc[kt][r]);
        #pragma unroll
        for (int off = 1; off < 16; off <<= 1) m = fmaxf(m, __shfl_xor(m, off));
        if (col == 0) rred[0][wv][quad * 4 + r] = m;
    }
    __syncthreads();
    #pragma unroll
    for (int r = 0; r < 4; ++r){
        int row = quad * 4 + r;
        float m = rred[0][0][row];
        #pragma unroll
        for (int w = 1; w < 8; ++w) m = fmaxf(m, rred[0][w][row]);
        #pragma unroll
        for (int kt = 0; kt < 8; ++kt) sc[kt][r] = __expf(sc[kt][r] - m);
    }
    #pragma unroll
    for (int r = 0; r < 4; ++r){
        float s = 0.f;
        #pragma unroll
        for (int kt = 0; kt < 8; ++kt) s += sc[kt][r];
        #pragma unroll
        for (int off = 1; off < 16; off <<= 1) s += __shfl_xor(s, off);
        if (col == 0) rred[1][wv][quad * 4 + r] = s;
    }

    // ---- PV: per-tile u32-packed transpose (P0|P1 in one dword) + 2 MFMAs
    v4f acc = {0.f, 0.f, 0.f, 0.f};
    uint32_t* tw = tls[wv];
    const int rdbase = col * 20 + 8 * (quad & 1);
    const uint32_t selp = (quad < 2) ? 0x05040100u : 0x07060302u;  // lo16s : hi16s
    #pragma unroll
    for (int kt = 0; kt < 8; ++kt){
        #pragma unroll
        for (int r = 0; r < 4; ++r){
            float x = sc[kt][r];
            uint32_t u0 = f2b_bits(x);
            uint32_t u1 = f2b_bits(x - b2f((u16)u0));
            tw[(quad * 4 + r) * 20 + col] = u0 | (u1 << 16);
        }
        __builtin_amdgcn_s_waitcnt(0xC07F);        // drain lgkm (wave-local transpose)
        uint4 d0 = *(const uint4*)&tw[rdbase];
        uint4 d1 = *(const uint4*)&tw[rdbase + 4];
        I4S ux;
        ux.i[0] = __builtin_amdgcn_perm(d0.y, d0.x, selp);
        ux.i[1] = __builtin_amdgcn_perm(d0.w, d0.z, selp);
        ux.i[2] = __builtin_amdgcn_perm(d1.y, d1.x, selp);
        ux.i[3] = __builtin_amdgcn_perm(d1.w, d1.z, selp);
        v8s ap = ux.s;                              // [P0|P1]
        int ktg = wv * 8 + kt;
        v8s bv1 = asv8s(VP1[fbase + (size_t)ktg * 64 + lane]);
        v8s bv2 = swapq(bv1);                      // [V1|V0]
        acc = __builtin_amdgcn_mfma_f32_16x16x32_bf16(ap, bv1, acc, 0, 0, 0); // P0V0+P1V1
        acc = __builtin_amdgcn_mfma_f32_16x16x32_bf16(ap, bv2, acc, 0, 0, 0); // P0V1+P1V0
    }
    #pragma unroll
    for (int r = 0; r < 4; ++r) pvred[wv][quad * 4 + r][col] = acc[r];

    // ---- top-8 extraction per wave strip (exact fp32 compares, idx tiebreak)
    #pragma unroll
    for (int r = 0; r < 4; ++r){
        int row = quad * 4 + r;
        #pragma unroll
        for (int rnd = 0; rnd < 8; ++rnd){
            float bv = sc[0][r]; int bk = 0;
            #pragma unroll
            for (int kt = 1; kt < 8; ++kt){
                bool g = sc[kt][r] > bv;
                bv = g ? sc[kt][r] : bv; bk = g ? kt : bk;
            }
            int bi = bk * 16 + col;
            #pragma unroll
            for (int off = 1; off < 16; off <<= 1){
                float ov = __shfl_xor(bv, off);
                int   oi = __shfl_xor(bi, off);
                bool g = (ov > bv) || (ov == bv && oi < bi);
                bv = g ? ov : bv; bi = g ? oi : bi;
            }
            if ((bi & 15) == col){
                int ktw = bi >> 4;
                #pragma unroll
                for (int kt = 0; kt < 8; ++kt)
                    if (kt == ktw) sc[kt][r] = -1.0f;
            }
            if (col == rnd){ tkv[wv][row][rnd] = bv; tki[wv][row][rnd] = wv * 128 + bi; }
        }
    }
    __syncthreads();

    // ---- msg0 write (256 thr) + 8-way top-k merge (16 thr)
    if (tid < 256){
        int row = tid >> 4, dd = tid & 15;
        float v = 0.f, s = 0.f;
        #pragma unroll
        for (int w = 0; w < 8; ++w){ v += pvred[w][row][dd]; s += rred[1][w][row]; }
        msg0[((size_t)((b * 1024 + lbase + row) * 8 + h)) * 16 + dd] = v / s;
    }
    if (tid < 16){
        int row = tid;
        int* tp = topk_out + (((b * 1024 + lbase + row) * 8 + h) * 8);
        int p[8] = {0,0,0,0,0,0,0,0};
        #pragma unroll
        for (int rnd = 0; rnd < 8; ++rnd){
            float bv = -3.0f; int bw = 0, bi = 0x7fffffff;
            #pragma unroll
            for (int w = 0; w < 8; ++w){
                float v = tkv[w][row][p[w]];
                int   i = tki[w][row][p[w]];
                bool g = (v > bv) || (v == bv && i < bi);
                bv = g ? v : bv; bi = g ? i : bi; bw = g ? w : bw;
            }
            tp[rnd] = bi;
            p[bw]++;
        }
    }
}

// ---------------------------------------------------------------------------
// Coarse fallback (round-5 version) — used only if ws too small.
// ---------------------------------------------------------------------------
__global__ __launch_bounds__(512, 2)
void coarse_kernel(const float* __restrict__ qc, const float* __restrict__ kc,
                   const float* __restrict__ vc, float* __restrict__ msg0,
                   int* __restrict__ topk_out)
{
    const int ltile = blockIdx.x;
    const int h = blockIdx.y, b = blockIdx.z;
    const int tid = threadIdx.x;
    const int lane = tid & 63, wv = tid >> 6;
    const int lbase = ltile * 32;
    __shared__ float sKV[16 * 1024];
    const size_t base = (size_t)(b * 128 + h * 16) * 1024;
    {
        const float4* gK = (const float4*)(kc + base);
        float4* lK = (float4*)sKV;
        #pragma unroll
        for (int i = 0; i < 8; ++i) lK[tid + 512 * i] = gK[tid + 512 * i];
    }
    float qreg[4];
    {
        int dq = lane & 15;
        #pragma unroll
        for (int li = 0; li < 4; ++li){
            int l = lbase + wv * 4 + li;
            qreg[li] = qc[base + (size_t)dq * 1024 + l] * TEMP;
        }
    }
    __syncthreads();
    float p[4][16];
    #pragma unroll
    for (int li = 0; li < 4; ++li)
        #pragma unroll
        for (int j = 0; j < 16; ++j) p[li][j] = 0.f;
    #pragma unroll
    for (int dch = 0; dch < 16; ++dch){
        float kf[16];
        #pragma unroll
        for (int ch = 0; ch < 4; ++ch){
            float4 kv = *(const float4*)&sKV[dch * 1024 + ch * 256 + (lane << 2)];
            kf[ch*4+0] = kv.x; kf[ch*4+1] = kv.y; kf[ch*4+2] = kv.z; kf[ch*4+3] = kv.w;
        }
        float qs[4];
        #pragma unroll
        for (int li = 0; li < 4; ++li) qs[li] = __shfl(qreg[li], dch);
        #pragma unroll
        for (int li = 0; li < 4; ++li)
            #pragma unroll
            for (int j = 0; j < 16; ++j) p[li][j] = fmaf(qs[li], kf[j], p[li][j]);
    }
    float invs[4];
    #pragma unroll
    for (int li = 0; li < 4; ++li){
        float m = p[li][0];
        #pragma unroll
        for (int j = 1; j < 16; ++j) m = fmaxf(m, p[li][j]);
        #pragma unroll
        for (int off = 32; off > 0; off >>= 1) m = fmaxf(m, __shfl_xor(m, off));
        float s = 0.f;
        #pragma unroll
        for (int j = 0; j < 16; ++j){ p[li][j] = __expf(p[li][j] - m); s += p[li][j]; }
        #pragma unroll
        for (int off = 32; off > 0; off >>= 1) s += __shfl_xor(s, off);
        invs[li] = 1.0f / s;
    }
    __syncthreads();
    {
        const float4* gV = (const float4*)(vc + base);
        float4* lV = (float4*)sKV;
        #pragma unroll
        for (int i = 0; i < 8; ++i) lV[tid + 512 * i] = gV[tid + 512 * i];
    }
    __syncthreads();
    float outv = 0.f;
    #pragma unroll
    for (int dd = 0; dd < 16; ++dd){
        float vf[16];
        #pragma unroll
        for (int ch = 0; ch < 4; ++ch){
            float4 vv = *(const float4*)&sKV[dd * 1024 + ch * 256 + (lane << 2)];
            vf[ch*4+0] = vv.x; vf[ch*4+1] = vv.y; vf[ch*4+2] = vv.z; vf[ch*4+3] = vv.w;
        }
        float a[4];
        #pragma unroll
        for (int li = 0; li < 4; ++li){
            float s = 0.f;
            #pragma unroll
            for (int j = 0; j < 16; ++j) s = fmaf(p[li][j], vf[j], s);
            a[li] = s;
        }
        #pragma unroll
        for (int off = 32; off > 0; off >>= 1)
            #pragma unroll
            for (int li = 0; li < 4; ++li) a[li] += __shfl_xor(a[li], off);
        #pragma unroll
        for (int li = 0; li < 4; ++li)
            outv = (lane == li * 16 + dd) ? a[li] * invs[li] : outv;
    }
    {
        int li = lane >> 4, dd = lane & 15;
        int l = lbase + wv * 4 + li;
        msg0[(size_t)((b * 1024 + l) * 8 + h) * 16 + dd] = outv;
    }
    const int lanebase = lane << 4;
    int mytk = 0;
    for (int r = 0; r < 8; ++r){
        float bv[4]; int bi[4];
        #pragma unroll
        for (int li = 0; li < 4; ++li){
            float v0[8]; int j0[8];
            #pragma unroll
            for (int k = 0; k < 8; ++k){
                bool g = p[li][2*k+1] > p[li][2*k];
                v0[k] = g ? p[li][2*k+1] : p[li][2*k];
                j0[k] = g ? 2*k+1 : 2*k;
            }
            float v1[4]; int j1[4];
            #pragma unroll
            for (int k = 0; k < 4; ++k){
                bool g = v0[2*k+1] > v0[2*k];
                v1[k] = g ? v0[2*k+1] : v0[2*k];
                j1[k] = g ? j0[2*k+1] : j0[2*k];
            }
            float v2[2]; int j2[2];
            #pragma unroll
            for (int k = 0; k < 2; ++k){
                bool g = v1[2*k+1] > v1[2*k];
                v2[k] = g ? v1[2*k+1] : v1[2*k];
                j2[k] = g ? j1[2*k+1] : j1[2*k];
            }
            bool g3 = v2[1] > v2[0];
            bv[li] = g3 ? v2[1] : v2[0];
            bi[li] = lanebase | (g3 ? j2[1] : j2[0]);
        }
        #pragma unroll
        for (int off = 32; off > 0; off >>= 1){
            #pragma unroll
            for (int li = 0; li < 4; ++li){
                float ov = __shfl_xor(bv[li], off);
                int   oi = __shfl_xor(bi[li], off);
                bool g = (ov > bv[li]) || (ov == bv[li] && oi < bi[li]);
                bv[li] = g ? ov : bv[li];
                bi[li] = g ? oi : bi[li];
            }
        }
        #pragma unroll
        for (int li = 0; li < 4; ++li){
            #pragma unroll
            for (int j = 0; j < 16; ++j)
                p[li][j] = (bi[li] == (lanebase | j)) ? -1.0f : p[li][j];
            mytk = (lane == li * 8 + r) ? bi[li] : mytk;
        }
    }
    if (lane < 32){
        int li = lane >> 3, r = lane & 7;
        int jw = mytk & 15, lw = mytk >> 4;
        int s = ((jw >> 2) << 8) | (lw << 2) | (jw & 3);
        int l = lbase + wv * 4 + li;
        topk_out[((b * 1024 + l) * 8 + h) * 8 + r] = s;
    }
}

// ---------------------------------------------------------------------------
// Fine-path pack (unchanged).
// ---------------------------------------------------------------------------
__global__ __launch_bounds__(256)
void pack_kernel(const float* __restrict__ kf, const float* __restrict__ vf,
                 const float* __restrict__ qf,
                 uint32_t* __restrict__ packed, float* __restrict__ qT)
{
    const int pt = blockIdx.x;
    const int b  = blockIdx.y;
    const int z  = blockIdx.z;
    const float* src = (z == 0) ? kf : (z == 1) ? vf : qf;
    const int tid = threadIdx.x;
    __shared__ float tile[64][129];
    const int pos0 = pt * 64;

    #pragma unroll
    for (int it = 0; it < 8; ++it){
        int task = it * 256 + tid;
        int ch = task >> 4, p4 = task & 15;
        float4 v = *(const float4*)(src + (size_t)(b * 128 + ch) * 4096 + pos0 + p4 * 4);
        tile[p4*4+0][ch] = v.x; tile[p4*4+1][ch] = v.y;
        tile[p4*4+2][ch] = v.z; tile[p4*4+3][ch] = v.w;
    }
    __syncthreads();

    if (z == 2){
        #pragma unroll
        for (int it = 0; it < 8; ++it){
            int task = it * 256 + tid;
            int p = task >> 5, c4 = task & 31;
            float4 v = make_float4(tile[p][c4*4+0], tile[p][c4*4+1],
                                   tile[p][c4*4+2], tile[p][c4*4+3]);
            *(float4*)(qT + ((size_t)(b * 4096) + pos0 + p) * 128 + c4 * 4) = v;
        }
    } else {
        const int x = pt;
        #pragma unroll
        for (int it = 0; it < 2; ++it){
            int task = it * 256 + tid;
            int h = task >> 6, y = task & 63;
            int pprime = ((x >> 1) * 32 + (y >> 1)) * 4 + (x & 1) * 2 + (y & 1);
            size_t line = (size_t)(b * 8 + h) * 4096 + pprime;
            uint32_t dw[8];
            #pragma unroll
            for (int i = 0; i < 8; ++i){
                uint32_t lo = f2b_bits(tile[y][h * 16 + 2 * i]);
                uint32_t hi = f2b_bits(tile[y][h * 16 + 2 * i + 1]);
                dw[i] = lo | (hi << 16);
            }
            uint4* dst4 = (uint4*)packed + line * 4 + z * 2;
            dst4[0] = make_uint4(dw[0], dw[1], dw[2], dw[3]);
            dst4[1] = make_uint4(dw[4], dw[5], dw[6], dw[7]);
        }
    }
}

// ---------------------------------------------------------------------------
// Fine level + combine (unchanged).
// ---------------------------------------------------------------------------
__global__ __launch_bounds__(256)
void fine_kernel(const float* __restrict__ qf, const float* __restrict__ kf,
                 const float* __restrict__ vf,
                 const float* __restrict__ qTg, const uint32_t* __restrict__ packed,
                 int transposed,
                 const float* __restrict__ wt,
                 const int* __restrict__ topk_in, const float* __restrict__ msg0,
                 float* __restrict__ out)
{
    const int l0 = blockIdx.x;
    const int b  = blockIdx.y;
    const int tid = threadIdx.x;

    __shared__ float vT[8][16][34];
    __shared__ float qT[8][4][16];
    __shared__ float pT[8][4][32];
    __shared__ int tkS[8][8];

    if (tid < 64) tkS[tid >> 3][tid & 7] =
        topk_in[((b * 1024 + l0) * 8 + (tid >> 3)) * 8 + (tid & 7)];
    __syncthreads();

    const int i = l0 >> 5, j = l0 & 31;
    const int hh = tid >> 5;
    const int t  = tid & 31;
    const int kk = t >> 2, cp = t & 3;

    float k[16];
    {
        int s = tkS[hh][kk];
        if (transposed){
            const uint4* pk = (const uint4*)packed;
            size_t line = (size_t)(b * 8 + hh) * 4096 + s * 4 + cp;
            uint4 a0 = pk[line*4+0], a1 = pk[line*4+1];
            uint4 a2 = pk[line*4+2], a3 = pk[line*4+3];
            k[0]=bl(a0.x);  k[1]=bh(a0.x);  k[2]=bl(a0.y);  k[3]=bh(a0.y);
            k[4]=bl(a0.z);  k[5]=bh(a0.z);  k[6]=bl(a0.w);  k[7]=bh(a0.w);
            k[8]=bl(a1.x);  k[9]=bh(a1.x);  k[10]=bl(a1.y); k[11]=bh(a1.y);
            k[12]=bl(a1.z); k[13]=bh(a1.z); k[14]=bl(a1.w); k[15]=bh(a1.w);
            vT[hh][0][t]=bl(a2.x);  vT[hh][1][t]=bh(a2.x);
            vT[hh][2][t]=bl(a2.y);  vT[hh][3][t]=bh(a2.y);
            vT[hh][4][t]=bl(a2.z);  vT[hh][5][t]=bh(a2.z);
            vT[hh][6][t]=bl(a2.w);  vT[hh][7][t]=bh(a2.w);
            vT[hh][8][t]=bl(a3.x);  vT[hh][9][t]=bh(a3.x);
            vT[hh][10][t]=bl(a3.y); vT[hh][11][t]=bh(a3.y);
            vT[hh][12][t]=bl(a3.z); vT[hh][13][t]=bh(a3.z);
            vT[hh][14][t]=bl(a3.w); vT[hh][15][t]=bh(a3.w);
        } else {
            int pos = (2 * (s >> 5) + (cp >> 1)) * 64 + 2 * (s & 31) + (cp & 1);
            size_t gb = (size_t)(b * 128 + hh * 16) * 4096 + pos;
            #pragma unroll
            for (int ch = 0; ch < 16; ++ch){
                k[ch] = kf[gb + (size_t)ch * 4096];
                vT[hh][ch][t] = vf[gb + (size_t)ch * 4096];
            }
        }
    }
    if (tid < 128){
        int qh = tid >> 4, aq = (tid >> 2) & 3, c4 = tid & 3;
        int qpos = (2 * i + (aq >> 1)) * 64 + 2 * j + (aq & 1);
        if (transposed){
            float4 u = *(const float4*)(qTg + ((size_t)(b * 4096) + qpos) * 128 + qh * 16 + c4 * 4);
            qT[qh][aq][c4*4+0] = u.x * TEMP;
            qT[qh][aq][c4*4+1] = u.y * TEMP;
            qT[qh][aq][c4*4+2] = u.z * TEMP;
            qT[qh][aq][c4*4+3] = u.w * TEMP;
        } else {
            #pragma unroll
            for (int c = 0; c < 4; ++c)
                qT[qh][aq][c4*4+c] =
                    qf[(size_t)(b * 128 + qh * 16 + c4 * 4 + c) * 4096 + qpos] * TEMP;
        }
    }
    __syncthreads();

    {
        float sc[4] = {0.f, 0.f, 0.f, 0.f};
        #pragma unroll
        for (int dch = 0; dch < 16; ++dch){
            float kv = k[dch];
            #pragma unroll
            for (int q = 0; q < 4; ++q) sc[q] = fmaf(qT[hh][q][dch], kv, sc[q]);
        }
        #pragma unroll
        for (int q = 0; q < 4; ++q){
            float m = sc[q];
            #pragma unroll
            for (int off = 16; off > 0; off >>= 1) m = fmaxf(m, __shfl_xor(m, off, 32));
            float e = __expf(sc[q] - m);
            float s = e;
            #pragma unroll
            for (int off = 16; off > 0; off >>= 1) s += __shfl_xor(s, off, 32);
            pT[hh][q][t] = e / s;
        }
    }
    __syncthreads();

    {
        float w0 = wt[0], w1 = wt[1];
        float mx = fmaxf(w0, w1);
        float e0 = __expf(w0 - mx), e1 = __expf(w1 - mx);
        float w0f = e0 / (e0 + e1), w1f = e1 / (e0 + e1);

        int q0 = (tid >> 4) & 1;
        int dd = tid & 15;
        float a0 = 0.f, a1 = 0.f;
        #pragma unroll
        for (int tt = 0; tt < 16; ++tt){
            float v0 = vT[hh][dd][tt * 2], v1 = vT[hh][dd][tt * 2 + 1];
            float2 pA = *(const float2*)&pT[hh][q0][tt * 2];
            float2 pB = *(const float2*)&pT[hh][q0 + 2][tt * 2];
            a0 = fmaf(pA.x, v0, a0); a0 = fmaf(pA.y, v1, a0);
            a1 = fmaf(pB.x, v0, a1); a1 = fmaf(pB.y, v1, a1);
        }
        float m0 = msg0[(size_t)((b * 1024 + l0) * 8 + hh) * 16 + dd];
        float o0 = w0f * m0 + w1f * a0;
        float o1 = w0f * m0 + w1f * a1;
        int posA = (2 * i) * 64 + 2 * j + q0;
        int posB = (2 * i + 1) * 64 + 2 * j + q0;
        out[(size_t)((b * 4096 + posA) * 8 + hh) * 16 + dd] = o0;
        out[(size_t)((b * 4096 + posB) * 8 + hh) * 16 + dd] = o1;
    }
}

extern "C" void kernel_launch(void* const* d_in, const int* in_sizes, int n_in,
                              void* d_out, int out_size, void* d_ws, size_t ws_size,
                              hipStream_t stream)
{
    (void)in_sizes; (void)n_in; (void)out_size;

    const float* q_fine   = (const float*)d_in[0];
    const float* q_coarse = (const float*)d_in[1];
    const float* k_fine   = (const float*)d_in[2];
    const float* k_coarse = (const float*)d_in[3];
    const float* v_fine   = (const float*)d_in[4];
    const float* v_coarse = (const float*)d_in[5];
    const float* weight   = (const float*)d_in[6];

    const size_t MB = 1024 * 1024;
    float*    msg0   = (float*)d_ws;                          // 2 MB
    int*      topk   = (int*)((char*)d_ws + 2 * MB);          // 1 MB
    float*    qT     = (float*)((char*)d_ws + 3 * MB);        // 8 MB
    uint32_t* packed = (uint32_t*)((char*)d_ws + 11 * MB);    // 8 MB
    uint4*    KP1    = (uint4*)((char*)d_ws + 19 * MB);       // 2 MB
    uint4*    KP3    = (uint4*)((char*)d_ws + 21 * MB);       // 2 MB
    uint4*    VP1    = (uint4*)((char*)d_ws + 23 * MB);       // 2 MB
    const int doT = (ws_size >= 19 * MB) ? 1 : 0;
    const int doM = (ws_size >= 25 * MB) ? 1 : 0;

    if (doM){
        pack_coarse<<<dim3(32, 2, 8), dim3(256), 0, stream>>>(k_coarse, v_coarse,
                                                              KP1, KP3, VP1);
        coarse_mfma<<<dim3(64, 8, 4), dim3(512), 0, stream>>>(q_coarse, KP1, KP3, VP1,
                                                              msg0, topk);
    } else {
        coarse_kernel<<<dim3(32, 8, 4), dim3(512), 0, stream>>>(q_coarse, k_coarse,
                                                                v_coarse, msg0, topk);
    }

    if (doT){
        pack_kernel<<<dim3(64, 4, 3), dim3(256), 0, stream>>>(k_fine, v_fine, q_fine,
                                                              packed, qT);
    }

    fine_kernel<<<dim3(1024, 4), dim3(256), 0, stream>>>(q_fine, k_fine, v_fine,
                                                         qT, packed, doT,
                                                         weight, topk, msg0,
                                                         (float*)d_out);
}

// Round 11
// 218.179 us; speedup vs baseline: 1.0780x; 1.0780x over previous
//
#include <hip/hip_runtime.h>
#include <stdint.h>

#define TEMP 0.25f   // 1/sqrt(d), d=16

typedef unsigned short u16;
typedef short v8s __attribute__((ext_vector_type(8)));
typedef float v4f __attribute__((ext_vector_type(4)));

static __device__ __forceinline__ uint32_t f2b_bits(float f){
    union { float f; uint32_t i; } x; x.f = f;
    uint32_t u = x.i;
    return (u + 0x7FFFu + ((u >> 16) & 1u)) >> 16;   // RNE to bf16 (as u16)
}
static __device__ __forceinline__ float b2f(u16 u){
    union { uint32_t i; float f; } x; x.i = ((uint32_t)u) << 16; return x.f;
}
static __device__ __forceinline__ float bl(uint32_t u){
    union { uint32_t i; float f; } x; x.i = u << 16; return x.f;
}
static __device__ __forceinline__ float bh(uint32_t u){
    union { uint32_t i; float f; } x; x.i = u & 0xffff0000u; return x.f;
}
static __device__ __forceinline__ uint4 pack8(const uint32_t* e){
    return make_uint4(e[0] | (e[1] << 16), e[2] | (e[3] << 16),
                      e[4] | (e[5] << 16), e[6] | (e[7] << 16));
}
union U8S { uint4 u; v8s s; };
union I4S { int i[4]; v8s s; };
static __device__ __forceinline__ v8s asv8s(uint4 u){ U8S x; x.u = u; return x.s; }
static __device__ __forceinline__ v8s swapq(v8s v){   // lane^32: [X|Y] -> [Y|X]
    union { v8s s; int i[4]; } x; x.s = v;
    #pragma unroll
    for (int k = 0; k < 4; ++k) x.i[k] = __shfl_xor(x.i[k], 32);
    return x.s;
}

// ---------------------------------------------------------------------------
// pack_coarse: K -> KP1=[K0|K1], KP3=[K2|K0]; V -> VP1=[V0|V1].
// Grid (32 bh, 2 kv, 8 kt-slice) = 512 blocks (latency-hidden).
// ---------------------------------------------------------------------------
__global__ __launch_bounds__(256)
void pack_coarse(const float* __restrict__ kc, const float* __restrict__ vc,
                 uint4* __restrict__ KP1, uint4* __restrict__ KP3,
                 uint4* __restrict__ VP1)
{
    const int bh = blockIdx.x;        // 0..31
    const int kv = blockIdx.y;        // 0:K 1:V
    const int z  = blockIdx.z;        // 0..7 (8 kt each)
    const int b = bh >> 3, h = bh & 7;
    const int tid = threadIdx.x;
    const size_t sbase = (size_t)(b * 128 + h * 16) * 1024;
    const size_t fbase = (size_t)bh * 64 * 64;

    #pragma unroll
    for (int it = 0; it < 2; ++it){
        int task = it * 256 + tid;
        int kt = z * 8 + (task >> 6), ln = task & 63;
        int quad = ln >> 4, col = ln & 15;
        if (kv == 0){
            uint32_t e1[8], e3[8];
            #pragma unroll
            for (int j = 0; j < 8; ++j){
                int dch = (quad & 1) * 8 + j;
                float x = kc[sbase + (size_t)dch * 1024 + kt * 16 + col];
                uint32_t u0 = f2b_bits(x);
                float r1 = x - b2f((u16)u0);
                uint32_t u1 = f2b_bits(r1);
                float r2 = r1 - b2f((u16)u1);
                uint32_t u2 = f2b_bits(r2);
                e1[j] = (quad < 2) ? u0 : u1;
                e3[j] = (quad < 2) ? u2 : u0;
            }
            KP1[fbase + kt * 64 + ln] = pack8(e1);
            KP3[fbase + kt * 64 + ln] = pack8(e3);
        } else {
            uint32_t e[8];
            #pragma unroll
            for (int j = 0; j < 8; ++j){
                int key = kt * 16 + (quad & 1) * 8 + j;
                float x = vc[sbase + (size_t)col * 1024 + key];
                uint32_t u0 = f2b_bits(x);
                uint32_t u1 = f2b_bits(x - b2f((u16)u0));
                e[j] = (quad < 2) ? u0 : u1;
            }
            VP1[fbase + kt * 64 + ln] = pack8(e);
        }
    }
}

// ---------------------------------------------------------------------------
// coarse_mfma v5: r7's 4-wave shape + r7's EXACT-fp32 top-k (hardware-proven;
// kt-embedded compares in r9/r10 flipped ~3 rows at the top-8 boundary ->
// 4.4e-2 errors — comparisons must be exact) + r8-proven perm-extracted
// two-term PV + parallel pack. Scores bit-identical to r7.
// ---------------------------------------------------------------------------
__global__ __launch_bounds__(256)
void coarse_mfma(const float* __restrict__ qc,
                 const uint4* __restrict__ KP1, const uint4* __restrict__ KP3,
                 const uint4* __restrict__ VP1,
                 float* __restrict__ msg0, int* __restrict__ topk_out)
{
    const int ltile = blockIdx.x;   // 0..63
    const int h = blockIdx.y, b = blockIdx.z;
    const int bh = b * 8 + h;
    const int tid = threadIdx.x, lane = tid & 63, wv = tid >> 6;  // wv 0..3
    const int quad = lane >> 4, col = lane & 15;
    const int lbase = ltile * 16;

    __shared__ uint32_t tls[4][16 * 20];   // packed P0|P1, stride 20 u32
    __shared__ float rred[2][4][16];       // [max|sum][wave][row]
    __shared__ float pvred[4][16][16];
    __shared__ float tkv[4][16][8];
    __shared__ int   tki[4][16][8];

    // ---- A-frags from Q (3-term bf16 split; TEMP folded in, exact pow2)
    v8s a1, a3;
    {
        int row = lbase + col;
        int dch0 = (quad & 1) * 8;
        #pragma unroll
        for (int j = 0; j < 8; ++j){
            float x = qc[(size_t)(b * 128 + h * 16 + dch0 + j) * 1024 + row] * TEMP;
            uint32_t u0 = f2b_bits(x);
            float r1 = x - b2f((u16)u0);
            uint32_t u1 = f2b_bits(r1);
            float r2 = r1 - b2f((u16)u1);
            uint32_t u2 = f2b_bits(r2);
            a1[j] = (short)(quad < 2 ? u0 : u1);
            a3[j] = (short)(quad < 2 ? u0 : u2);
        }
    }

    // ---- scores: 16 C-tiles (rows lbase.., cols = keys wv*256 + kt*16 + col)
    const size_t fbase = (size_t)bh * 64 * 64;
    v4f sc[16];
    #pragma unroll
    for (int kt = 0; kt < 16; ++kt){
        int ktg = wv * 16 + kt;
        v8s b1 = asv8s(KP1[fbase + (size_t)ktg * 64 + lane]);
        v8s b3 = asv8s(KP3[fbase + (size_t)ktg * 64 + lane]);
        v8s b2 = swapq(b1);                         // [K1|K0]
        v4f c = {0.f, 0.f, 0.f, 0.f};
        c = __builtin_amdgcn_mfma_f32_16x16x32_bf16(a1, b1, c, 0, 0, 0); // Q0K0+Q1K1
        c = __builtin_amdgcn_mfma_f32_16x16x32_bf16(a1, b2, c, 0, 0, 0); // Q0K1+Q1K0
        c = __builtin_amdgcn_mfma_f32_16x16x32_bf16(a3, b3, c, 0, 0, 0); // Q0K2+Q2K0
        sc[kt] = c;
    }

    // ---- softmax: global row max -> exp -> row sums (unnormalized P kept)
    #pragma unroll
    for (int r = 0; r < 4; ++r){
        float m = sc[0][r];
        #pragma unroll
        for (int kt = 1; kt < 16; ++kt) m = fmaxf(m, sc[kt][r]);
        #pragma unroll
        for (int off = 1; off < 16; off <<= 1) m = fmaxf(m, __shfl_xor(m, off));
        if (col == 0) rred[0][wv][quad * 4 + r] = m;
    }
    __syncthreads();
    #pragma unroll
    for (int r = 0; r < 4; ++r){
        int row = quad * 4 + r;
        float m = fmaxf(fmaxf(rred[0][0][row], rred[0][1][row]),
                        fmaxf(rred[0][2][row], rred[0][3][row]));
        #pragma unroll
        for (int kt = 0; kt < 16; ++kt) sc[kt][r] = __expf(sc[kt][r] - m);
    }
    #pragma unroll
    for (int r = 0; r < 4; ++r){
        float s = 0.f;
        #pragma unroll
        for (int kt = 0; kt < 16; ++kt) s += sc[kt][r];
        #pragma unroll
        for (int off = 1; off < 16; off <<= 1) s += __shfl_xor(s, off);
        if (col == 0) rred[1][wv][quad * 4 + r] = s;
    }

    // ---- PV: two-term bf16 P (r8-proven): store u0|u1<<16, quad-selected
    // perm extraction, 2 MFMAs with swapped V.
    v4f acc = {0.f, 0.f, 0.f, 0.f};
    uint32_t* tw = tls[wv];
    const int rdbase = col * 20 + 8 * (quad & 1);
    const uint32_t selp = (quad < 2) ? 0x05040100u : 0x07060302u;  // P0 : P1
    #pragma unroll
    for (int kt = 0; kt < 16; ++kt){
        #pragma unroll
        for (int r = 0; r < 4; ++r){
            float x = sc[kt][r];
            uint32_t u0 = f2b_bits(x);
            uint32_t u1 = f2b_bits(x - b2f((u16)u0));
            tw[(quad * 4 + r) * 20 + col] = u0 | (u1 << 16);
        }
        __builtin_amdgcn_s_waitcnt(0xC07F);        // drain lgkm (wave-local)
        uint4 d0 = *(const uint4*)&tw[rdbase];
        uint4 d1 = *(const uint4*)&tw[rdbase + 4];
        I4S ux;
        ux.i[0] = __builtin_amdgcn_perm(d0.y, d0.x, selp);
        ux.i[1] = __builtin_amdgcn_perm(d0.w, d0.z, selp);
        ux.i[2] = __builtin_amdgcn_perm(d1.y, d1.x, selp);
        ux.i[3] = __builtin_amdgcn_perm(d1.w, d1.z, selp);
        v8s ap = ux.s;                              // [P0|P1]
        v8s bv1 = asv8s(VP1[fbase + (size_t)(wv * 16 + kt) * 64 + lane]);
        v8s bv2 = swapq(bv1);                       // [V1|V0]
        acc = __builtin_amdgcn_mfma_f32_16x16x32_bf16(ap, bv1, acc, 0, 0, 0); // P0V0+P1V1
        acc = __builtin_amdgcn_mfma_f32_16x16x32_bf16(ap, bv2, acc, 0, 0, 0); // P0V1+P1V0
    }
    #pragma unroll
    for (int r = 0; r < 4; ++r) pvred[wv][quad * 4 + r][col] = acc[r];

    // ---- top-8: EXACT fp32 compares with explicit (value,index) butterfly
    // (r7's hardware-proven block — no value perturbation, idx tie-break).
    #pragma unroll
    for (int r = 0; r < 4; ++r){
        int row = quad * 4 + r;
        #pragma unroll
        for (int rnd = 0; rnd < 8; ++rnd){
            float bv = sc[0][r]; int bk = 0;
            #pragma unroll
            for (int kt = 1; kt < 16; ++kt){
                bool g = sc[kt][r] > bv;
                bv = g ? sc[kt][r] : bv; bk = g ? kt : bk;
            }
            int bi = bk * 16 + col;
            #pragma unroll
            for (int off = 1; off < 16; off <<= 1){
                float ov = __shfl_xor(bv, off);
                int   oi = __shfl_xor(bi, off);
                bool g = (ov > bv) || (ov == bv && oi < bi);
                bv = g ? ov : bv; bi = g ? oi : bi;
            }
            if ((bi & 15) == col){
                int ktw = bi >> 4;
                #pragma unroll
                for (int kt = 0; kt < 16; ++kt)
                    if (kt == ktw) sc[kt][r] = -1.0f;
            }
            if (col == rnd){ tkv[wv][row][rnd] = bv; tki[wv][row][rnd] = wv * 256 + bi; }
        }
    }
    __syncthreads();

    // ---- msg0 write (256 thr) + 4-way top-k merge (16 thr)
    {
        int row = tid >> 4, dd = tid & 15;
        float v = pvred[0][row][dd] + pvred[1][row][dd] +
                  pvred[2][row][dd] + pvred[3][row][dd];
        float s = rred[1][0][row] + rred[1][1][row] +
                  rred[1][2][row] + rred[1][3][row];
        msg0[((size_t)((b * 1024 + lbase + row) * 8 + h)) * 16 + dd] = v / s;
    }
    if (tid < 16){
        int row = tid;
        int* tp = topk_out + (((b * 1024 + lbase + row) * 8 + h) * 8);
        int p[4] = {0, 0, 0, 0};
        #pragma unroll
        for (int rnd = 0; rnd < 8; ++rnd){
            float bv = -3.0f; int bw = 0, bi = 0x7fffffff;
            #pragma unroll
            for (int w = 0; w < 4; ++w){
                float v = tkv[w][row][p[w]];
                int   i = tki[w][row][p[w]];
                bool g = (v > bv) || (v == bv && i < bi);
                bv = g ? v : bv; bi = g ? i : bi; bw = g ? w : bw;
            }
            tp[rnd] = bi;
            p[bw]++;
        }
    }
}

// ---------------------------------------------------------------------------
// Coarse fallback (round-5 version) — used only if ws too small.
// ---------------------------------------------------------------------------
__global__ __launch_bounds__(512, 2)
void coarse_kernel(const float* __restrict__ qc, const float* __restrict__ kc,
                   const float* __restrict__ vc, float* __restrict__ msg0,
                   int* __restrict__ topk_out)
{
    const int ltile = blockIdx.x;
    const int h = blockIdx.y, b = blockIdx.z;
    const int tid = threadIdx.x;
    const int lane = tid & 63, wv = tid >> 6;
    const int lbase = ltile * 32;
    __shared__ float sKV[16 * 1024];
    const size_t base = (size_t)(b * 128 + h * 16) * 1024;
    {
        const float4* gK = (const float4*)(kc + base);
        float4* lK = (float4*)sKV;
        #pragma unroll
        for (int i = 0; i < 8; ++i) lK[tid + 512 * i] = gK[tid + 512 * i];
    }
    float qreg[4];
    {
        int dq = lane & 15;
        #pragma unroll
        for (int li = 0; li < 4; ++li){
            int l = lbase + wv * 4 + li;
            qreg[li] = qc[base + (size_t)dq * 1024 + l] * TEMP;
        }
    }
    __syncthreads();
    float p[4][16];
    #pragma unroll
    for (int li = 0; li < 4; ++li)
        #pragma unroll
        for (int j = 0; j < 16; ++j) p[li][j] = 0.f;
    #pragma unroll
    for (int dch = 0; dch < 16; ++dch){
        float kf[16];
        #pragma unroll
        for (int ch = 0; ch < 4; ++ch){
            float4 kv = *(const float4*)&sKV[dch * 1024 + ch * 256 + (lane << 2)];
            kf[ch*4+0] = kv.x; kf[ch*4+1] = kv.y; kf[ch*4+2] = kv.z; kf[ch*4+3] = kv.w;
        }
        float qs[4];
        #pragma unroll
        for (int li = 0; li < 4; ++li) qs[li] = __shfl(qreg[li], dch);
        #pragma unroll
        for (int li = 0; li < 4; ++li)
            #pragma unroll
            for (int j = 0; j < 16; ++j) p[li][j] = fmaf(qs[li], kf[j], p[li][j]);
    }
    float invs[4];
    #pragma unroll
    for (int li = 0; li < 4; ++li){
        float m = p[li][0];
        #pragma unroll
        for (int j = 1; j < 16; ++j) m = fmaxf(m, p[li][j]);
        #pragma unroll
        for (int off = 32; off > 0; off >>= 1) m = fmaxf(m, __shfl_xor(m, off));
        float s = 0.f;
        #pragma unroll
        for (int j = 0; j < 16; ++j){ p[li][j] = __expf(p[li][j] - m); s += p[li][j]; }
        #pragma unroll
        for (int off = 32; off > 0; off >>= 1) s += __shfl_xor(s, off);
        invs[li] = 1.0f / s;
    }
    __syncthreads();
    {
        const float4* gV = (const float4*)(vc + base);
        float4* lV = (float4*)sKV;
        #pragma unroll
        for (int i = 0; i < 8; ++i) lV[tid + 512 * i] = gV[tid + 512 * i];
    }
    __syncthreads();
    float outv = 0.f;
    #pragma unroll
    for (int dd = 0; dd < 16; ++dd){
        float vf[16];
        #pragma unroll
        for (int ch = 0; ch < 4; ++ch){
            float4 vv = *(const float4*)&sKV[dd * 1024 + ch * 256 + (lane << 2)];
            vf[ch*4+0] = vv.x; vf[ch*4+1] = vv.y; vf[ch*4+2] = vv.z; vf[ch*4+3] = vv.w;
        }
        float a[4];
        #pragma unroll
        for (int li = 0; li < 4; ++li){
            float s = 0.f;
            #pragma unroll
            for (int j = 0; j < 16; ++j) s = fmaf(p[li][j], vf[j], s);
            a[li] = s;
        }
        #pragma unroll
        for (int off = 32; off > 0; off >>= 1)
            #pragma unroll
            for (int li = 0; li < 4; ++li) a[li] += __shfl_xor(a[li], off);
        #pragma unroll
        for (int li = 0; li < 4; ++li)
            outv = (lane == li * 16 + dd) ? a[li] * invs[li] : outv;
    }
    {
        int li = lane >> 4, dd = lane & 15;
        int l = lbase + wv * 4 + li;
        msg0[(size_t)((b * 1024 + l) * 8 + h) * 16 + dd] = outv;
    }
    const int lanebase = lane << 4;
    int mytk = 0;
    for (int r = 0; r < 8; ++r){
        float bv[4]; int bi[4];
        #pragma unroll
        for (int li = 0; li < 4; ++li){
            float v0[8]; int j0[8];
            #pragma unroll
            for (int k = 0; k < 8; ++k){
                bool g = p[li][2*k+1] > p[li][2*k];
                v0[k] = g ? p[li][2*k+1] : p[li][2*k];
                j0[k] = g ? 2*k+1 : 2*k;
            }
            float v1[4]; int j1[4];
            #pragma unroll
            for (int k = 0; k < 4; ++k){
                bool g = v0[2*k+1] > v0[2*k];
                v1[k] = g ? v0[2*k+1] : v0[2*k];
                j1[k] = g ? j0[2*k+1] : j0[2*k];
            }
            float v2[2]; int j2[2];
            #pragma unroll
            for (int k = 0; k < 2; ++k){
                bool g = v1[2*k+1] > v1[2*k];
                v2[k] = g ? v1[2*k+1] : v1[2*k];
                j2[k] = g ? j1[2*k+1] : j1[2*k];
            }
            bool g3 = v2[1] > v2[0];
            bv[li] = g3 ? v2[1] : v2[0];
            bi[li] = lanebase | (g3 ? j2[1] : j2[0]);
        }
        #pragma unroll
        for (int off = 32; off > 0; off >>= 1){
            #pragma unroll
            for (int li = 0; li < 4; ++li){
                float ov = __shfl_xor(bv[li], off);
                int   oi = __shfl_xor(bi[li], off);
                bool g = (ov > bv[li]) || (ov == bv[li] && oi < bi[li]);
                bv[li] = g ? ov : bv[li];
                bi[li] = g ? oi : bi[li];
            }
        }
        #pragma unroll
        for (int li = 0; li < 4; ++li){
            #pragma unroll
            for (int j = 0; j < 16; ++j)
                p[li][j] = (bi[li] == (lanebase | j)) ? -1.0f : p[li][j];
            mytk = (lane == li * 8 + r) ? bi[li] : mytk;
        }
    }
    if (lane < 32){
        int li = lane >> 3, r = lane & 7;
        int jw = mytk & 15, lw = mytk >> 4;
        int s = ((jw >> 2) << 8) | (lw << 2) | (jw & 3);
        int l = lbase + wv * 4 + li;
        topk_out[((b * 1024 + l) * 8 + h) * 8 + r] = s;
    }
}

// ---------------------------------------------------------------------------
// Fine-path pack (unchanged).
// ---------------------------------------------------------------------------
__global__ __launch_bounds__(256)
void pack_kernel(const float* __restrict__ kf, const float* __restrict__ vf,
                 const float* __restrict__ qf,
                 uint32_t* __restrict__ packed, float* __restrict__ qT)
{
    const int pt = blockIdx.x;
    const int b  = blockIdx.y;
    const int z  = blockIdx.z;
    const float* src = (z == 0) ? kf : (z == 1) ? vf : qf;
    const int tid = threadIdx.x;
    __shared__ float tile[64][129];
    const int pos0 = pt * 64;

    #pragma unroll
    for (int it = 0; it < 8; ++it){
        int task = it * 256 + tid;
        int ch = task >> 4, p4 = task & 15;
        float4 v = *(const float4*)(src + (size_t)(b * 128 + ch) * 4096 + pos0 + p4 * 4);
        tile[p4*4+0][ch] = v.x; tile[p4*4+1][ch] = v.y;
        tile[p4*4+2][ch] = v.z; tile[p4*4+3][ch] = v.w;
    }
    __syncthreads();

    if (z == 2){
        #pragma unroll
        for (int it = 0; it < 8; ++it){
            int task = it * 256 + tid;
            int p = task >> 5, c4 = task & 31;
            float4 v = make_float4(tile[p][c4*4+0], tile[p][c4*4+1],
                                   tile[p][c4*4+2], tile[p][c4*4+3]);
            *(float4*)(qT + ((size_t)(b * 4096) + pos0 + p) * 128 + c4 * 4) = v;
        }
    } else {
        const int x = pt;
        #pragma unroll
        for (int it = 0; it < 2; ++it){
            int task = it * 256 + tid;
            int h = task >> 6, y = task & 63;
            int pprime = ((x >> 1) * 32 + (y >> 1)) * 4 + (x & 1) * 2 + (y & 1);
            size_t line = (size_t)(b * 8 + h) * 4096 + pprime;
            uint32_t dw[8];
            #pragma unroll
            for (int i = 0; i < 8; ++i){
                uint32_t lo = f2b_bits(tile[y][h * 16 + 2 * i]);
                uint32_t hi = f2b_bits(tile[y][h * 16 + 2 * i + 1]);
                dw[i] = lo | (hi << 16);
            }
            uint4* dst4 = (uint4*)packed + line * 4 + z * 2;
            dst4[0] = make_uint4(dw[0], dw[1], dw[2], dw[3]);
            dst4[1] = make_uint4(dw[4], dw[5], dw[6], dw[7]);
        }
    }
}

// ---------------------------------------------------------------------------
// Fine level + combine (unchanged).
// ---------------------------------------------------------------------------
__global__ __launch_bounds__(256)
void fine_kernel(const float* __restrict__ qf, const float* __restrict__ kf,
                 const float* __restrict__ vf,
                 const float* __restrict__ qTg, const uint32_t* __restrict__ packed,
                 int transposed,
                 const float* __restrict__ wt,
                 const int* __restrict__ topk_in, const float* __restrict__ msg0,
                 float* __restrict__ out)
{
    const int l0 = blockIdx.x;
    const int b  = blockIdx.y;
    const int tid = threadIdx.x;

    __shared__ float vT[8][16][34];
    __shared__ float qT[8][4][16];
    __shared__ float pT[8][4][32];
    __shared__ int tkS[8][8];

    if (tid < 64) tkS[tid >> 3][tid & 7] =
        topk_in[((b * 1024 + l0) * 8 + (tid >> 3)) * 8 + (tid & 7)];
    __syncthreads();

    const int i = l0 >> 5, j = l0 & 31;
    const int hh = tid >> 5;
    const int t  = tid & 31;
    const int kk = t >> 2, cp = t & 3;

    float k[16];
    {
        int s = tkS[hh][kk];
        if (transposed){
            const uint4* pk = (const uint4*)packed;
            size_t line = (size_t)(b * 8 + hh) * 4096 + s * 4 + cp;
            uint4 a0 = pk[line*4+0], a1 = pk[line*4+1];
            uint4 a2 = pk[line*4+2], a3 = pk[line*4+3];
            k[0]=bl(a0.x);  k[1]=bh(a0.x);  k[2]=bl(a0.y);  k[3]=bh(a0.y);
            k[4]=bl(a0.z);  k[5]=bh(a0.z);  k[6]=bl(a0.w);  k[7]=bh(a0.w);
            k[8]=bl(a1.x);  k[9]=bh(a1.x);  k[10]=bl(a1.y); k[11]=bh(a1.y);
            k[12]=bl(a1.z); k[13]=bh(a1.z); k[14]=bl(a1.w); k[15]=bh(a1.w);
            vT[hh][0][t]=bl(a2.x);  vT[hh][1][t]=bh(a2.x);
            vT[hh][2][t]=bl(a2.y);  vT[hh][3][t]=bh(a2.y);
            vT[hh][4][t]=bl(a2.z);  vT[hh][5][t]=bh(a2.z);
            vT[hh][6][t]=bl(a2.w);  vT[hh][7][t]=bh(a2.w);
            vT[hh][8][t]=bl(a3.x);  vT[hh][9][t]=bh(a3.x);
            vT[hh][10][t]=bl(a3.y); vT[hh][11][t]=bh(a3.y);
            vT[hh][12][t]=bl(a3.z); vT[hh][13][t]=bh(a3.z);
            vT[hh][14][t]=bl(a3.w); vT[hh][15][t]=bh(a3.w);
        } else {
            int pos = (2 * (s >> 5) + (cp >> 1)) * 64 + 2 * (s & 31) + (cp & 1);
            size_t gb = (size_t)(b * 128 + hh * 16) * 4096 + pos;
            #pragma unroll
            for (int ch = 0; ch < 16; ++ch){
                k[ch] = kf[gb + (size_t)ch * 4096];
                vT[hh][ch][t] = vf[gb + (size_t)ch * 4096];
            }
        }
    }
    if (tid < 128){
        int qh = tid >> 4, aq = (tid >> 2) & 3, c4 = tid & 3;
        int qpos = (2 * i + (aq >> 1)) * 64 + 2 * j + (aq & 1);
        if (transposed){
            float4 u = *(const float4*)(qTg + ((size_t)(b * 4096) + qpos) * 128 + qh * 16 + c4 * 4);
            qT[qh][aq][c4*4+0] = u.x * TEMP;
            qT[qh][aq][c4*4+1] = u.y * TEMP;
            qT[qh][aq][c4*4+2] = u.z * TEMP;
            qT[qh][aq][c4*4+3] = u.w * TEMP;
        } else {
            #pragma unroll
            for (int c = 0; c < 4; ++c)
                qT[qh][aq][c4*4+c] =
                    qf[(size_t)(b * 128 + qh * 16 + c4 * 4 + c) * 4096 + qpos] * TEMP;
        }
    }
    __syncthreads();

    {
        float sc[4] = {0.f, 0.f, 0.f, 0.f};
        #pragma unroll
        for (int dch = 0; dch < 16; ++dch){
            float kv = k[dch];
            #pragma unroll
            for (int q = 0; q < 4; ++q) sc[q] = fmaf(qT[hh][q][dch], kv, sc[q]);
        }
        #pragma unroll
        for (int q = 0; q < 4; ++q){
            float m = sc[q];
            #pragma unroll
            for (int off = 16; off > 0; off >>= 1) m = fmaxf(m, __shfl_xor(m, off, 32));
            float e = __expf(sc[q] - m);
            float s = e;
            #pragma unroll
            for (int off = 16; off > 0; off >>= 1) s += __shfl_xor(s, off, 32);
            pT[hh][q][t] = e / s;
        }
    }
    __syncthreads();

    {
        float w0 = wt[0], w1 = wt[1];
        float mx = fmaxf(w0, w1);
        float e0 = __expf(w0 - mx), e1 = __expf(w1 - mx);
        float w0f = e0 / (e0 + e1), w1f = e1 / (e0 + e1);

        int q0 = (tid >> 4) & 1;
        int dd = tid & 15;
        float a0 = 0.f, a1 = 0.f;
        #pragma unroll
        for (int tt = 0; tt < 16; ++tt){
            float v0 = vT[hh][dd][tt * 2], v1 = vT[hh][dd][tt * 2 + 1];
            float2 pA = *(const float2*)&pT[hh][q0][tt * 2];
            float2 pB = *(const float2*)&pT[hh][q0 + 2][tt * 2];
            a0 = fmaf(pA.x, v0, a0); a0 = fmaf(pA.y, v1, a0);
            a1 = fmaf(pB.x, v0, a1); a1 = fmaf(pB.y, v1, a1);
        }
        float m0 = msg0[(size_t)((b * 1024 + l0) * 8 + hh) * 16 + dd];
        float o0 = w0f * m0 + w1f * a0;
        float o1 = w0f * m0 + w1f * a1;
        int posA = (2 * i) * 64 + 2 * j + q0;
        int posB = (2 * i + 1) * 64 + 2 * j + q0;
        out[(size_t)((b * 4096 + posA) * 8 + hh) * 16 + dd] = o0;
        out[(size_t)((b * 4096 + posB) * 8 + hh) * 16 + dd] = o1;
    }
}

extern "C" void kernel_launch(void* const* d_in, const int* in_sizes, int n_in,
                              void* d_out, int out_size, void* d_ws, size_t ws_size,
                              hipStream_t stream)
{
    (void)in_sizes; (void)n_in; (void)out_size;

    const float* q_fine   = (const float*)d_in[0];
    const float* q_coarse = (const float*)d_in[1];
    const float* k_fine   = (const float*)d_in[2];
    const float* k_coarse = (const float*)d_in[3];
    const float* v_fine   = (const float*)d_in[4];
    const float* v_coarse = (const float*)d_in[5];
    const float* weight   = (const float*)d_in[6];

    const size_t MB = 1024 * 1024;
    float*    msg0   = (float*)d_ws;                          // 2 MB
    int*      topk   = (int*)((char*)d_ws + 2 * MB);          // 1 MB
    float*    qT     = (float*)((char*)d_ws + 3 * MB);        // 8 MB
    uint32_t* packed = (uint32_t*)((char*)d_ws + 11 * MB);    // 8 MB
    uint4*    KP1    = (uint4*)((char*)d_ws + 19 * MB);       // 2 MB
    uint4*    KP3    = (uint4*)((char*)d_ws + 21 * MB);       // 2 MB
    uint4*    VP1    = (uint4*)((char*)d_ws + 23 * MB);       // 2 MB
    const int doT = (ws_size >= 19 * MB) ? 1 : 0;
    const int doM = (ws_size >= 25 * MB) ? 1 : 0;

    if (doM){
        pack_coarse<<<dim3(32, 2, 8), dim3(256), 0, stream>>>(k_coarse, v_coarse,
                                                              KP1, KP3, VP1);
        coarse_mfma<<<dim3(64, 8, 4), dim3(256), 0, stream>>>(q_coarse, KP1, KP3, VP1,
                                                              msg0, topk);
    } else {
        coarse_kernel<<<dim3(32, 8, 4), dim3(512), 0, stream>>>(q_coarse, k_coarse,
                                                                v_coarse, msg0, topk);
    }

    if (doT){
        pack_kernel<<<dim3(64, 4, 3), dim3(256), 0, stream>>>(k_fine, v_fine, q_fine,
                                                              packed, qT);
    }

    fine_kernel<<<dim3(1024, 4), dim3(256), 0, stream>>>(q_fine, k_fine, v_fine,
                                                         qT, packed, doT,
                                                         weight, topk, msg0,
                                                         (float*)d_out);
}